// Round 3
// baseline (381.651 us; speedup 1.0000x reference)
//
#include <hip/hip_runtime.h>

// LocalPredictor: 3x3 conv (32->128, center masked) + ReLU + 1x1 conv (128->32)
// B=8, k=32, H=W=256, HID=128. fp32 in/out (values bf16-exact) -> bf16 MFMA.
// v8 = swapped-operand GEMM1: mfma(A=w1, B=z) -> D1[d][x]; each wave owns a
// 16-wide x-slice and computes ALL 128 d for it. h becomes wave-local:
//  - h transport = per-wave LDS scratch, NO barrier (same-wave RAW ordering)
//  - barriers: 2/iter -> 1/iter (z-ring commit only; 4-slot ring is safe)
//  - z LDS reads: 32 -> 8 ds_read_b128 per wave-iter
//  - w1t frags 64 loads/wave-iter, tap-sequential footprint 8KB -> L1-hot
//  - numerics bit-identical to verified v7 (bias post-add, same orders)

#define KC 32
#define HH 256
#define WW 256
#define HID 128
#define YS 8
#define ZROW 2640   // 66 cols * 40 (c-stride)
#define HSTR 136    // h scratch leading dim (shorts)

typedef __attribute__((ext_vector_type(8))) short short8;
typedef __attribute__((ext_vector_type(4))) float f32x4;

// LDS-visibility barrier WITHOUT vmcnt drain: global loads/stores stay in flight.
#define BARRIER() asm volatile("s_waitcnt lgkmcnt(0)\n\ts_barrier" ::: "memory")
#define SCHED_FENCE() asm volatile("" ::: "memory")

__device__ __forceinline__ unsigned short f2bf(float f) {
    union { float f; unsigned int i; } x; x.f = f;
    unsigned int r = x.i + 0x7FFFu + ((x.i >> 16) & 1u);  // RNE
    return (unsigned short)(r >> 16);
}

// pack 8 bf16-exact floats -> short8 (truncate = exact)
__device__ __forceinline__ short8 pack8(const float* v) {
    union { short8 s; unsigned int u[4]; } w;
    union { float f; unsigned int i; } uu[8];
#pragma unroll
    for (int j = 0; j < 8; ++j) uu[j].f = v[j];
#pragma unroll
    for (int k = 0; k < 4; ++k)
        w.u[k] = __builtin_amdgcn_perm(uu[2 * k + 1].i, uu[2 * k].i, 0x07060302u);
    return w.s;
}

// ws: w1t bf16[9*HID*KC] | w2t bf16[KC*HID].  w1t[p][d][c], c contiguous.
__global__ void prep_weights(const float* __restrict__ w1,
                             const float* __restrict__ w2,
                             unsigned short* __restrict__ w1t,
                             unsigned short* __restrict__ w2t) {
    int i = blockIdx.x * 256 + threadIdx.x;
    if (i < 9 * HID * KC) {
        int c = i & 31;
        int d = (i >> 5) & 127;
        int p = i >> 12;
        w1t[i] = f2bf(w1[d * (9 * KC) + c * 9 + p]);
    } else if (i < 9 * HID * KC + KC * HID) {
        int j = i - 9 * HID * KC;
        w2t[j] = f2bf(w2[j]);
    }
}

__global__ __launch_bounds__(256, 4) void local_pred_kernel(
    const float* __restrict__ zg,
    const unsigned short* __restrict__ w1t,
    const float* __restrict__ b1g,
    const unsigned short* __restrict__ w2t,
    const float* __restrict__ b2g,
    float* __restrict__ outg)
{
    __shared__ __attribute__((aligned(16))) unsigned short z_lds[4 * ZROW];      // 21120 B
    __shared__ __attribute__((aligned(16))) unsigned short h_scr[64 * HSTR];     // 17408 B (per-wave 16 rows)
    __shared__ __attribute__((aligned(16))) unsigned short halo_lds[7 * 2 * 32]; //   896 B

    const int tid  = threadIdx.x;
    const int bidx = blockIdx.x;
    const int x0 = (bidx & 3) << 6;
    const int y0 = ((bidx >> 2) & 31) * YS;
    const int b  = bidx >> 7;

    const int l = tid & 63;       // staging x-lane
    const int o = tid >> 6;       // staging c-octet

    const int wave = tid >> 6;
    const int lane = tid & 63;
    const int lr = lane & 15;
    const int lq = lane >> 4;

    const float* zb = zg + (size_t)b * KC * HH * WW;

    // ---------------- prologue: sequential fenced rounds (low reg pressure) ----------------
    // main rows y0-1 .. y0+1
#pragma unroll
    for (int dy = 0; dy < 3; ++dy) {
        const int gy = y0 - 1 + dy;
        const bool ok = (unsigned)gy < (unsigned)HH;
        const int gyc = ok ? gy : 0;
        const float* p = zb + ((size_t)(o * 8) * HH + gyc) * WW + x0 + l;
        float t8[8];
#pragma unroll
        for (int j = 0; j < 8; ++j) t8[j] = ok ? p[(size_t)j * HH * WW] : 0.f;
        *(short8*)&z_lds[(dy * 66 + l + 1) * 40 + o * 8] = pack8(t8);
        SCHED_FENCE();
    }
    // near halo (rows y0-1..y0+1): tid<24 -> (side, c-octet, dy)
    {
        const int s = tid & 1, oc = (tid >> 1) & 3, dy = tid >> 3;
        const int gy = y0 - 1 + dy;
        const int gx = x0 - 1 + s * 65;
        const bool ok = (tid < 24) && ((unsigned)gy < (unsigned)HH) &&
                        ((unsigned)gx < (unsigned)WW);
        const float* q = zb + ((size_t)(oc * 8) * HH + (ok ? gy : 0)) * WW + (ok ? gx : 0);
        float t8[8];
#pragma unroll
        for (int j = 0; j < 8; ++j) t8[j] = ok ? q[(size_t)j * HH * WW] : 0.f;
        if (tid < 24)
            *(short8*)&z_lds[(dy * 66 + s * 65) * 40 + oc * 8] = pack8(t8);
        SCHED_FENCE();
    }
    // far halo (rows y0+2..y0+8): tid in [64,120) -> (side, c-octet, row)
    {
        const int fi = tid - 64;
        const int s = fi & 1, oc = (fi >> 1) & 3, fr = fi >> 3;
        const int gy = y0 + 2 + fr;
        const int gx = x0 - 1 + s * 65;
        const bool ok = (tid >= 64) && (tid < 120) && (gy < HH) &&
                        ((unsigned)gx < (unsigned)WW);
        const float* q = zb + ((size_t)(oc * 8) * HH + (ok ? gy : 0)) * WW + (ok ? gx : 0);
        float t8[8];
#pragma unroll
        for (int j = 0; j < 8; ++j) t8[j] = ok ? q[(size_t)j * HH * WW] : 0.f;
        if (tid >= 64 && tid < 120)
            *(short8*)&halo_lds[(fr * 2 + s) * 32 + oc * 8] = pack8(t8);
        SCHED_FENCE();
    }

    // hoisted bias2 (2 regs); b1 loaded per-iter from L1 (f32x4, post-add = v7 numerics)
    float bias2[2];
#pragma unroll
    for (int nt = 0; nt < 2; ++nt) bias2[nt] = b2g[nt * 16 + lr];

    BARRIER();

    const int tap_di[8] = {0, 0, 0, 1, 1, 2, 2, 2};
    const int tap_dj[8] = {0, 1, 2, 0, 2, 0, 1, 2};

    float mv8[8];   // single distance-1 prefetch buffer

    const int hbase = (wave * 16 + lr) * HSTR;   // per-wave x-row in h scratch

#pragma unroll
    for (int r = 0; r < YS; ++r) {
        const int y = y0 + r;
        const int S0 = r & 3, S1 = (r + 1) & 3, S2 = (r + 2) & 3, S3 = (r + 3) & 3;

        // ---------- issue prefetch: row y+2 (consumed at commit, end of this iter) ----------
        if (r < 7) {
            const int gy = y + 2;
            const bool ok = gy < HH;
            const float* p = zb + ((size_t)(o * 8) * HH + (ok ? gy : 0)) * WW + x0 + l;
#pragma unroll
            for (int j = 0; j < 8; ++j) mv8[j] = ok ? p[(size_t)j * HH * WW] : 0.f;
        }
        SCHED_FENCE();

        // ---------- GEMM1 (swapped): D1[d][x], per wave x-slice=16, all d=128 ----------
        // A = w1 (d x c): lane holds w1[d=nt*16+lr][c=lq*8..+7]  (same read as v7 bfr)
        // B = z  (c x x): lane holds z[c=lq*8..+7][x=wave*16+lr+dj-1]
        f32x4 acc[8];
#pragma unroll
        for (int nt = 0; nt < 8; ++nt)
            acc[nt] = (f32x4){0.f, 0.f, 0.f, 0.f};

        const int rowoff[3] = {S0 * ZROW, S1 * ZROW, S2 * ZROW};
#pragma unroll
        for (int t = 0; t < 8; ++t) {
            const int di = tap_di[t], dj = tap_dj[t];
            const int p = di * 3 + dj;
            short8 zfr = *(const short8*)&z_lds[rowoff[di] + (wave * 16 + lr + dj) * 40 + lq * 8];
#pragma unroll
            for (int nt = 0; nt < 8; ++nt) {
                short8 wfr = *(const short8*)&w1t[p * (HID * KC) + (nt * 16 + lr) * KC + lq * 8];
                acc[nt] = __builtin_amdgcn_mfma_f32_16x16x32_bf16(wfr, zfr, acc[nt], 0, 0, 0);
            }
        }

        // ---------- epilogue1: +b1 (post-add, v7 order), ReLU, pack pairs -> wave-local h ----------
        // lane holds h[d = nt*16 + lq*4 + rr][x = wave*16 + lr]
#pragma unroll
        for (int nt = 0; nt < 8; ++nt) {
            const f32x4 bv = *(const f32x4*)&b1g[nt * 16 + lq * 4];
#pragma unroll
            for (int e = 0; e < 2; ++e) {
                float v0 = acc[nt][2 * e]     + bv[2 * e];
                float v1 = acc[nt][2 * e + 1] + bv[2 * e + 1];
                v0 = v0 > 0.f ? v0 : 0.f;
                v1 = v1 > 0.f ? v1 : 0.f;
                unsigned int pk = ((unsigned int)f2bf(v1) << 16) | f2bf(v0);
                *(unsigned int*)&h_scr[hbase + nt * 16 + lq * 4 + 2 * e] = pk;
            }
        }
        // wave-local RAW: compiler orders ds_write -> ds_read with lgkmcnt. NO barrier.

        // ---------- GEMM2: D2[x][kout], A = h (x × d) wave-local, B = w2 ----------
        f32x4 acc2[2];
        acc2[0] = (f32x4){0.f, 0.f, 0.f, 0.f};
        acc2[1] = (f32x4){0.f, 0.f, 0.f, 0.f};
#pragma unroll
        for (int kk = 0; kk < 4; ++kk) {
            short8 afr = *(const short8*)&h_scr[hbase + kk * 32 + lq * 8];
#pragma unroll
            for (int nt = 0; nt < 2; ++nt) {
                short8 bfr = *(const short8*)&w2t[(nt * 16 + lr) * HID + kk * 32 + lq * 8];
                acc2[nt] = __builtin_amdgcn_mfma_f32_16x16x32_bf16(afr, bfr, acc2[nt], 0, 0, 0);
            }
        }

        // ---------- epilogue2: +b2, 16B coalesced stores (same mapping as v7) ----------
#pragma unroll
        for (int nt = 0; nt < 2; ++nt) {
            const int kout = nt * 16 + lr;
            f32x4 pk;
#pragma unroll
            for (int rr = 0; rr < 4; ++rr) pk[rr] = acc2[nt][rr] + bias2[nt];
            const int mb = wave * 16 + lq * 4;
            const size_t off = ((size_t)(b * KC + kout) * HH + y) * WW + x0 + mb;
            *(f32x4*)&outg[off] = pk;
        }

        // ---------- commit prefetched row y+2 into slot S3 ----------
        if (r < 7) {
            *(short8*)&z_lds[(S3 * 66 + l + 1) * 40 + o * 8] = pack8(mv8);
            if (tid < 8) {
                const int side = tid & 1, oct = tid >> 1;
                short8 hv = *(const short8*)&halo_lds[(r * 2 + side) * 32 + oct * 8];
                *(short8*)&z_lds[(S3 * 66 + side * 65) * 40 + oct * 8] = hv;
            }
        }
        BARRIER();   // single barrier/iter: commit visible before next iter's reads
    }
}

extern "C" void kernel_launch(void* const* d_in, const int* in_sizes, int n_in,
                              void* d_out, int out_size, void* d_ws, size_t ws_size,
                              hipStream_t stream)
{
    const float* z  = (const float*)d_in[0];
    const float* W1 = (const float*)d_in[1];
    const float* b1 = (const float*)d_in[2];
    const float* W2 = (const float*)d_in[3];
    const float* b2 = (const float*)d_in[4];
    float* out = (float*)d_out;
    unsigned short* w1t = (unsigned short*)d_ws;                // 73728 B
    unsigned short* w2t = (unsigned short*)d_ws + 9 * HID * KC; // + 8192 B

    hipLaunchKernelGGL(prep_weights, dim3(160), dim3(256), 0, stream, W1, W2, w1t, w2t);
    hipLaunchKernelGGL(local_pred_kernel, dim3(8 * 4 * (HH / YS)), dim3(256), 0, stream,
                       z, w1t, b1, w2t, b2, out);
}

// Round 5
// 313.907 us; speedup vs baseline: 1.2158x; 1.2158x over previous
//
#include <hip/hip_runtime.h>

// LocalPredictor: 3x3 conv (32->128, center masked) + ReLU + 1x1 conv (128->32)
// B=8, k=32, H=W=256, HID=128. fp32 in/out (values bf16-exact) -> bf16 MFMA.
// v10 = v9's halved-register swapped-operand structure + v8's PROVEN h layout:
//  - v9 failed (absmax 1.44): h rows at 132B stride -> 4B-aligned ds_read_b128
//    (every passing version had >=8B-aligned h rows) + cross-half WAR on h.
//  - v10 restores HSTR=136 (272B rows, 16B-aligned, v8-proven) and gives each
//    d-half its own offset range (hf*64+...): both suspects eliminated.
//  - still: acc[4] per half (16 regs), wave-local h, 1 barrier/iter,
//    GEMM2 k-order = v7's 0..3 -> bit-identical numerics.

#define KC 32
#define HH 256
#define WW 256
#define HID 128
#define YS 8
#define ZROW 2640   // 66 cols * 40 (c-stride)
#define HSTR 136    // h_scr leading dim (shorts); 272B = 16B-aligned rows

typedef __attribute__((ext_vector_type(8))) short short8;
typedef __attribute__((ext_vector_type(4))) float f32x4;

// LDS-visibility barrier WITHOUT vmcnt drain: global loads/stores stay in flight.
#define BARRIER() asm volatile("s_waitcnt lgkmcnt(0)\n\ts_barrier" ::: "memory")
#define SCHED_FENCE() asm volatile("" ::: "memory")

__device__ __forceinline__ unsigned short f2bf(float f) {
    union { float f; unsigned int i; } x; x.f = f;
    unsigned int r = x.i + 0x7FFFu + ((x.i >> 16) & 1u);  // RNE
    return (unsigned short)(r >> 16);
}

// pack 8 bf16-exact floats -> short8 (truncate = exact)
__device__ __forceinline__ short8 pack8(const float* v) {
    union { short8 s; unsigned int u[4]; } w;
    union { float f; unsigned int i; } uu[8];
#pragma unroll
    for (int j = 0; j < 8; ++j) uu[j].f = v[j];
#pragma unroll
    for (int k = 0; k < 4; ++k)
        w.u[k] = __builtin_amdgcn_perm(uu[2 * k + 1].i, uu[2 * k].i, 0x07060302u);
    return w.s;
}

// ws: w1t bf16[9*HID*KC] | w2t bf16[KC*HID].  w1t[p][d][c], c contiguous.
__global__ void prep_weights(const float* __restrict__ w1,
                             const float* __restrict__ w2,
                             unsigned short* __restrict__ w1t,
                             unsigned short* __restrict__ w2t) {
    int i = blockIdx.x * 256 + threadIdx.x;
    if (i < 9 * HID * KC) {
        int c = i & 31;
        int d = (i >> 5) & 127;
        int p = i >> 12;
        w1t[i] = f2bf(w1[d * (9 * KC) + c * 9 + p]);
    } else if (i < 9 * HID * KC + KC * HID) {
        int j = i - 9 * HID * KC;
        w2t[j] = f2bf(w2[j]);
    }
}

__global__ __launch_bounds__(256, 3) void local_pred_kernel(
    const float* __restrict__ zg,
    const unsigned short* __restrict__ w1t,
    const float* __restrict__ b1g,
    const unsigned short* __restrict__ w2t,
    const float* __restrict__ b2g,
    float* __restrict__ outg)
{
    __shared__ __attribute__((aligned(16))) unsigned short z_lds[4 * ZROW];      // 21120 B
    __shared__ __attribute__((aligned(16))) unsigned short h_scr[64 * HSTR];     // 17408 B
    __shared__ __attribute__((aligned(16))) unsigned short halo_lds[7 * 2 * 32]; //   896 B

    const int tid  = threadIdx.x;
    const int bidx = blockIdx.x;
    const int x0 = (bidx & 3) << 6;
    const int y0 = ((bidx >> 2) & 31) * YS;
    const int b  = bidx >> 7;

    const int l = tid & 63;       // staging x-lane
    const int o = tid >> 6;       // staging c-octet

    const int wave = tid >> 6;
    const int lane = tid & 63;
    const int lr = lane & 15;
    const int lq = lane >> 4;

    const float* zb = zg + (size_t)b * KC * HH * WW;

    // ---------------- prologue: sequential fenced rounds (low reg pressure) ----------------
    // main rows y0-1 .. y0+1
#pragma unroll
    for (int dy = 0; dy < 3; ++dy) {
        const int gy = y0 - 1 + dy;
        const bool ok = (unsigned)gy < (unsigned)HH;
        const int gyc = ok ? gy : 0;
        const float* p = zb + ((size_t)(o * 8) * HH + gyc) * WW + x0 + l;
        float t8[8];
#pragma unroll
        for (int j = 0; j < 8; ++j) t8[j] = ok ? p[(size_t)j * HH * WW] : 0.f;
        *(short8*)&z_lds[(dy * 66 + l + 1) * 40 + o * 8] = pack8(t8);
        SCHED_FENCE();
    }
    // near halo (rows y0-1..y0+1): tid<24 -> (side, c-octet, dy)
    {
        const int s = tid & 1, oc = (tid >> 1) & 3, dy = tid >> 3;
        const int gy = y0 - 1 + dy;
        const int gx = x0 - 1 + s * 65;
        const bool ok = (tid < 24) && ((unsigned)gy < (unsigned)HH) &&
                        ((unsigned)gx < (unsigned)WW);
        const float* q = zb + ((size_t)(oc * 8) * HH + (ok ? gy : 0)) * WW + (ok ? gx : 0);
        float t8[8];
#pragma unroll
        for (int j = 0; j < 8; ++j) t8[j] = ok ? q[(size_t)j * HH * WW] : 0.f;
        if (tid < 24)
            *(short8*)&z_lds[(dy * 66 + s * 65) * 40 + oc * 8] = pack8(t8);
        SCHED_FENCE();
    }
    // far halo (rows y0+2..y0+8): tid in [64,120) -> (side, c-octet, row)
    {
        const int fi = tid - 64;
        const int s = fi & 1, oc = (fi >> 1) & 3, fr = fi >> 3;
        const int gy = y0 + 2 + fr;
        const int gx = x0 - 1 + s * 65;
        const bool ok = (tid >= 64) && (tid < 120) && (gy < HH) &&
                        ((unsigned)gx < (unsigned)WW);
        const float* q = zb + ((size_t)(oc * 8) * HH + (ok ? gy : 0)) * WW + (ok ? gx : 0);
        float t8[8];
#pragma unroll
        for (int j = 0; j < 8; ++j) t8[j] = ok ? q[(size_t)j * HH * WW] : 0.f;
        if (tid >= 64 && tid < 120)
            *(short8*)&halo_lds[(fr * 2 + s) * 32 + oc * 8] = pack8(t8);
        SCHED_FENCE();
    }

    // hoisted bias2 (2 regs); b1 loaded per-half from L1 (f32x4, post-add = v7 numerics)
    float bias2[2];
#pragma unroll
    for (int nt = 0; nt < 2; ++nt) bias2[nt] = b2g[nt * 16 + lr];

    BARRIER();

    const int tap_di[8] = {0, 0, 0, 1, 1, 2, 2, 2};
    const int tap_dj[8] = {0, 1, 2, 0, 2, 0, 1, 2};

    float mv8[8];   // single distance-1 prefetch buffer

    const int hbase = (wave * 16 + lr) * HSTR;   // per-wave x-row in h scratch

#pragma unroll
    for (int r = 0; r < YS; ++r) {
        const int y = y0 + r;
        const int S0 = r & 3, S1 = (r + 1) & 3, S2 = (r + 2) & 3, S3 = (r + 3) & 3;

        // ---------- issue prefetch: row y+2 (consumed at commit, end of this iter) ----------
        if (r < 7) {
            const int gy = y + 2;
            const bool ok = gy < HH;
            const float* p = zb + ((size_t)(o * 8) * HH + (ok ? gy : 0)) * WW + x0 + l;
#pragma unroll
            for (int j = 0; j < 8; ++j) mv8[j] = ok ? p[(size_t)j * HH * WW] : 0.f;
        }
        SCHED_FENCE();

        const int rowoff[3] = {S0 * ZROW, S1 * ZROW, S2 * ZROW};

        // GEMM2 accumulators persist across both d-halves (k order = v7's k4 0..3)
        f32x4 acc2[2];
        acc2[0] = (f32x4){0.f, 0.f, 0.f, 0.f};
        acc2[1] = (f32x4){0.f, 0.f, 0.f, 0.f};

#pragma unroll
        for (int hf = 0; hf < 2; ++hf) {
            // ---------- GEMM1 half (swapped): D1[d-half][x], acc[4] = 16 regs ----------
            // A = w1 (d x c): lane holds w1[d=hf*64+nt*16+lr][c=lq*8..+7]
            // B = z  (c x x): lane holds z[c=lq*8..+7][x=wave*16+lr+dj-1]
            f32x4 acc[4];
#pragma unroll
            for (int nt = 0; nt < 4; ++nt)
                acc[nt] = (f32x4){0.f, 0.f, 0.f, 0.f};

#pragma unroll
            for (int t = 0; t < 8; ++t) {
                const int di = tap_di[t], dj = tap_dj[t];
                const int p = di * 3 + dj;
                short8 zfr = *(const short8*)&z_lds[rowoff[di] + (wave * 16 + lr + dj) * 40 + lq * 8];
#pragma unroll
                for (int nt = 0; nt < 4; ++nt) {
                    short8 wfr = *(const short8*)&w1t[p * (HID * KC) + (hf * 64 + nt * 16 + lr) * KC + lq * 8];
                    acc[nt] = __builtin_amdgcn_mfma_f32_16x16x32_bf16(wfr, zfr, acc[nt], 0, 0, 0);
                }
            }

            // ---------- epilogue1 half: +b1 (post-add), ReLU, pack pairs -> wave-local h ----------
            // lane holds h[d = hf*64 + nt*16 + lq*4 + rr][x = wave*16 + lr]
            // write at this half's own offsets (hf*64+...): no cross-half overlap
#pragma unroll
            for (int nt = 0; nt < 4; ++nt) {
                const f32x4 bv = *(const f32x4*)&b1g[hf * 64 + nt * 16 + lq * 4];
#pragma unroll
                for (int e = 0; e < 2; ++e) {
                    float v0 = acc[nt][2 * e]     + bv[2 * e];
                    float v1 = acc[nt][2 * e + 1] + bv[2 * e + 1];
                    v0 = v0 > 0.f ? v0 : 0.f;
                    v1 = v1 > 0.f ? v1 : 0.f;
                    unsigned int pk = ((unsigned int)f2bf(v1) << 16) | f2bf(v0);
                    *(unsigned int*)&h_scr[hbase + hf * 64 + nt * 16 + lq * 4 + 2 * e] = pk;
                }
            }
            // wave-local RAW: compiler orders ds_write -> ds_read via lgkmcnt. NO barrier.

            // ---------- GEMM2 partial: k = hf*64 .. hf*64+63 (16B-aligned reads) ----------
#pragma unroll
            for (int kk = 0; kk < 2; ++kk) {
                short8 afr = *(const short8*)&h_scr[hbase + hf * 64 + kk * 32 + lq * 8];
#pragma unroll
                for (int nt = 0; nt < 2; ++nt) {
                    short8 bfr = *(const short8*)&w2t[(nt * 16 + lr) * HID + hf * 64 + kk * 32 + lq * 8];
                    acc2[nt] = __builtin_amdgcn_mfma_f32_16x16x32_bf16(afr, bfr, acc2[nt], 0, 0, 0);
                }
            }
            SCHED_FENCE();   // cap cross-half register hoisting
        }

        // ---------- epilogue2: +b2, 16B coalesced stores (v8-proven mapping) ----------
#pragma unroll
        for (int nt = 0; nt < 2; ++nt) {
            const int kout = nt * 16 + lr;
            f32x4 pk;
#pragma unroll
            for (int rr = 0; rr < 4; ++rr) pk[rr] = acc2[nt][rr] + bias2[nt];
            const int mb = wave * 16 + lq * 4;
            const size_t off = ((size_t)(b * KC + kout) * HH + y) * WW + x0 + mb;
            *(f32x4*)&outg[off] = pk;
        }

        // ---------- commit prefetched row y+2 into slot S3 ----------
        if (r < 7) {
            *(short8*)&z_lds[(S3 * 66 + l + 1) * 40 + o * 8] = pack8(mv8);
            if (tid < 8) {
                const int side = tid & 1, oct = tid >> 1;
                short8 hv = *(const short8*)&halo_lds[(r * 2 + side) * 32 + oct * 8];
                *(short8*)&z_lds[(S3 * 66 + side * 65) * 40 + oct * 8] = hv;
            }
        }
        BARRIER();   // single barrier/iter: commit visible before next iter's reads
    }
}

extern "C" void kernel_launch(void* const* d_in, const int* in_sizes, int n_in,
                              void* d_out, int out_size, void* d_ws, size_t ws_size,
                              hipStream_t stream)
{
    const float* z  = (const float*)d_in[0];
    const float* W1 = (const float*)d_in[1];
    const float* b1 = (const float*)d_in[2];
    const float* W2 = (const float*)d_in[3];
    const float* b2 = (const float*)d_in[4];
    float* out = (float*)d_out;
    unsigned short* w1t = (unsigned short*)d_ws;                // 73728 B
    unsigned short* w2t = (unsigned short*)d_ws + 9 * HID * KC; // + 8192 B

    hipLaunchKernelGGL(prep_weights, dim3(160), dim3(256), 0, stream, W1, W2, w1t, w2t);
    hipLaunchKernelGGL(local_pred_kernel, dim3(8 * 4 * (HH / YS)), dim3(256), 0, stream,
                       z, w1t, b1, w2t, b2, out);
}

// Round 7
// 227.749 us; speedup vs baseline: 1.6758x; 1.3783x over previous
//
#include <hip/hip_runtime.h>

// LocalPredictor: 3x3 conv (32->128, center masked) + ReLU + 1x1 conv (128->32)
// B=8, k=32, H=W=256, HID=128. fp32 in/out (values bf16-exact) -> bf16 MFMA.
// v12 = v7 (109us proven) with HALF-WIDTH BLOCKS: 128 threads (2 waves),
// x-tile 32, grid 2048 (8 blocks/CU, one full round).
//  - single-variable test of the barrier-convoy theory: 8 independent 2-wave
//    barrier domains per CU instead of 4 four-wave ones.
//  - fragment layouts, tap order, GEMM2 k-order, barrier placement, 4-slot
//    ring all byte-identical to v7 -> identical numerics.
//  - per-wave N-split: wave owns d-half (wave*64 + nt*16+lr, nt 0..3);
//    M=32 (mt 0..1). acc[2][4] = 32 regs, same total as v7's acc[4][2].
//  - LDS 20.2KB -> 8 blocks/CU; regs 64+32=96 -> 4 waves/SIMD = 16 waves ok.

#define KC 32
#define HH 256
#define WW 256
#define HID 128
#define YS 8
#define XT 32       // x-tile width
#define ZROW 1360   // 34 cols * 40 (c-stride)
#define HSTR 132    // h_lds leading dim (shorts), proven in v7

typedef __attribute__((ext_vector_type(8))) short short8;
typedef __attribute__((ext_vector_type(4))) float f32x4;

// LDS-visibility barrier WITHOUT vmcnt drain: global loads/stores stay in flight.
#define BARRIER() asm volatile("s_waitcnt lgkmcnt(0)\n\ts_barrier" ::: "memory")
#define SCHED_FENCE() asm volatile("" ::: "memory")

__device__ __forceinline__ unsigned short f2bf(float f) {
    union { float f; unsigned int i; } x; x.f = f;
    unsigned int r = x.i + 0x7FFFu + ((x.i >> 16) & 1u);  // RNE
    return (unsigned short)(r >> 16);
}

// pack 8 bf16-exact floats -> short8 (truncate = exact)
__device__ __forceinline__ short8 pack8(const float* v) {
    union { short8 s; unsigned int u[4]; } w;
    union { float f; unsigned int i; } uu[8];
#pragma unroll
    for (int j = 0; j < 8; ++j) uu[j].f = v[j];
#pragma unroll
    for (int k = 0; k < 4; ++k)
        w.u[k] = __builtin_amdgcn_perm(uu[2 * k + 1].i, uu[2 * k].i, 0x07060302u);
    return w.s;
}

// ws: w1t bf16[9*HID*KC] | w2t bf16[KC*HID].  w1t[p][d][c], c contiguous.
__global__ void prep_weights(const float* __restrict__ w1,
                             const float* __restrict__ w2,
                             unsigned short* __restrict__ w1t,
                             unsigned short* __restrict__ w2t) {
    int i = blockIdx.x * 256 + threadIdx.x;
    if (i < 9 * HID * KC) {
        int c = i & 31;
        int d = (i >> 5) & 127;
        int p = i >> 12;
        w1t[i] = f2bf(w1[d * (9 * KC) + c * 9 + p]);
    } else if (i < 9 * HID * KC + KC * HID) {
        int j = i - 9 * HID * KC;
        w2t[j] = f2bf(w2[j]);
    }
}

__global__ __launch_bounds__(128, 4) void local_pred_kernel(
    const float* __restrict__ zg,
    const unsigned short* __restrict__ w1t,
    const float* __restrict__ b1g,
    const unsigned short* __restrict__ w2t,
    const float* __restrict__ b2g,
    float* __restrict__ outg)
{
    __shared__ __attribute__((aligned(16))) unsigned short z_lds[4 * ZROW];      // 10880 B
    __shared__ __attribute__((aligned(16))) unsigned short h_lds[32 * HSTR];     //  8448 B
    __shared__ __attribute__((aligned(16))) unsigned short halo_lds[7 * 2 * 32]; //   896 B

    const int tid  = threadIdx.x;
    const int bidx = blockIdx.x;
    const int x0 = (bidx & 7) << 5;          // 8 x-tiles of 32
    const int y0 = ((bidx >> 3) & 31) * YS;
    const int b  = bidx >> 8;

    const int l = tid & 31;       // staging x-lane (32 cols)
    const int o = tid >> 5;       // staging c-octet (0..3)

    const int wave = tid >> 6;    // 0..1
    const int lane = tid & 63;
    const int lr = lane & 15;
    const int lq = lane >> 4;

    const float* zb = zg + (size_t)b * KC * HH * WW;

    // ---------------- prologue: sequential fenced rounds (low reg pressure) ----------------
    // main rows y0-1 .. y0+1
#pragma unroll
    for (int dy = 0; dy < 3; ++dy) {
        const int gy = y0 - 1 + dy;
        const bool ok = (unsigned)gy < (unsigned)HH;
        const int gyc = ok ? gy : 0;
        const float* p = zb + ((size_t)(o * 8) * HH + gyc) * WW + x0 + l;
        float t8[8];
#pragma unroll
        for (int j = 0; j < 8; ++j) t8[j] = ok ? p[(size_t)j * HH * WW] : 0.f;
        *(short8*)&z_lds[(dy * 34 + l + 1) * 40 + o * 8] = pack8(t8);
        SCHED_FENCE();
    }
    // near halo (rows y0-1..y0+1): tid<24 -> (side, c-octet, dy)
    {
        const int s = tid & 1, oc = (tid >> 1) & 3, dy = tid >> 3;
        const int gy = y0 - 1 + dy;
        const int gx = x0 - 1 + s * 33;
        const bool ok = (tid < 24) && ((unsigned)gy < (unsigned)HH) &&
                        ((unsigned)gx < (unsigned)WW);
        const float* q = zb + ((size_t)(oc * 8) * HH + (ok ? gy : 0)) * WW + (ok ? gx : 0);
        float t8[8];
#pragma unroll
        for (int j = 0; j < 8; ++j) t8[j] = ok ? q[(size_t)j * HH * WW] : 0.f;
        if (tid < 24)
            *(short8*)&z_lds[(dy * 34 + s * 33) * 40 + oc * 8] = pack8(t8);
        SCHED_FENCE();
    }
    // far halo (rows y0+2..y0+8): tid in [64,120) -> (side, c-octet, row)
    {
        const int fi = tid - 64;
        const int s = fi & 1, oc = (fi >> 1) & 3, fr = fi >> 3;
        const int gy = y0 + 2 + fr;
        const int gx = x0 - 1 + s * 33;
        const bool ok = (tid >= 64) && (tid < 120) && (gy < HH) &&
                        ((unsigned)gx < (unsigned)WW);
        const float* q = zb + ((size_t)(oc * 8) * HH + (ok ? gy : 0)) * WW + (ok ? gx : 0);
        float t8[8];
#pragma unroll
        for (int j = 0; j < 8; ++j) t8[j] = ok ? q[(size_t)j * HH * WW] : 0.f;
        if (tid >= 64 && tid < 120)
            *(short8*)&halo_lds[(fr * 2 + s) * 32 + oc * 8] = pack8(t8);
        SCHED_FENCE();
    }

    // hoisted biases: wave owns d-half -> bias1[4]; bias2[2]
    float bias1[4], bias2[2];
#pragma unroll
    for (int nt = 0; nt < 4; ++nt) bias1[nt] = b1g[wave * 64 + nt * 16 + lr];
#pragma unroll
    for (int nt = 0; nt < 2; ++nt) bias2[nt] = b2g[nt * 16 + lr];

    BARRIER();

    const int tap_di[8] = {0, 0, 0, 1, 1, 2, 2, 2};
    const int tap_dj[8] = {0, 1, 2, 0, 2, 0, 1, 2};

    float mv8[8];   // single distance-1 prefetch buffer

#pragma unroll
    for (int r = 0; r < YS; ++r) {
        const int y = y0 + r;
        const int S0 = r & 3, S1 = (r + 1) & 3, S2 = (r + 2) & 3, S3 = (r + 3) & 3;

        // ---------- issue prefetch: row y+2 (consumed at commit, end of this iter) ----------
        if (r < 7) {
            const int gy = y + 2;
            const bool ok = gy < HH;
            const float* p = zb + ((size_t)(o * 8) * HH + (ok ? gy : 0)) * WW + x0 + l;
#pragma unroll
            for (int j = 0; j < 8; ++j) mv8[j] = ok ? p[(size_t)j * HH * WW] : 0.f;
        }
        SCHED_FENCE();

        // ---------- GEMM1: per wave M=32 (mt 0..1), d-half (nt 0..3) ----------
        f32x4 acc[2][4];
#pragma unroll
        for (int mt = 0; mt < 2; ++mt)
#pragma unroll
            for (int nt = 0; nt < 4; ++nt)
                acc[mt][nt] = (f32x4){0.f, 0.f, 0.f, 0.f};

        const int rowoff[3] = {S0 * ZROW, S1 * ZROW, S2 * ZROW};
#pragma unroll
        for (int t = 0; t < 8; ++t) {
            const int di = tap_di[t], dj = tap_dj[t];
            const int p = di * 3 + dj;
            short8 afr[2];
#pragma unroll
            for (int mt = 0; mt < 2; ++mt)
                afr[mt] = *(const short8*)&z_lds[rowoff[di] + (mt * 16 + lr + dj) * 40 + lq * 8];
            short8 bfr[4];
#pragma unroll
            for (int nt = 0; nt < 4; ++nt)
                bfr[nt] = *(const short8*)&w1t[p * (HID * KC) + (wave * 64 + nt * 16 + lr) * KC + lq * 8];
#pragma unroll
            for (int nt = 0; nt < 4; ++nt)
#pragma unroll
                for (int mt = 0; mt < 2; ++mt)
                    acc[mt][nt] = __builtin_amdgcn_mfma_f32_16x16x32_bf16(
                        afr[mt], bfr[nt], acc[mt][nt], 0, 0, 0);
        }

        // ---------- epilogue1: +b1, ReLU, bf16 -> h ----------
#pragma unroll
        for (int nt = 0; nt < 4; ++nt) {
            const int d = wave * 64 + nt * 16 + lr;
#pragma unroll
            for (int mt = 0; mt < 2; ++mt)
#pragma unroll
                for (int rr = 0; rr < 4; ++rr) {
                    float v = acc[mt][nt][rr] + bias1[nt];
                    v = v > 0.f ? v : 0.f;
                    const int m = mt * 16 + lq * 4 + rr;
                    h_lds[m * HSTR + d] = f2bf(v);
                }
        }
        BARRIER();   // h ready; all waves' GEMM1 z-reads complete

        // ---------- GEMM2: M=32, N=32, K=128 (B from L1-hot w2t) ----------
        f32x4 acc2[2];
        acc2[0] = (f32x4){0.f, 0.f, 0.f, 0.f};
        acc2[1] = (f32x4){0.f, 0.f, 0.f, 0.f};
        const int m2 = wave * 16 + lr;
#pragma unroll
        for (int k4 = 0; k4 < 4; ++k4) {
            short8 afr = *(const short8*)&h_lds[m2 * HSTR + k4 * 32 + lq * 8];
#pragma unroll
            for (int nt = 0; nt < 2; ++nt) {
                short8 bfr = *(const short8*)&w2t[(nt * 16 + lr) * HID + k4 * 32 + lq * 8];
                acc2[nt] = __builtin_amdgcn_mfma_f32_16x16x32_bf16(afr, bfr, acc2[nt], 0, 0, 0);
            }
        }

        // ---------- epilogue2: +b2, 16B coalesced stores ----------
#pragma unroll
        for (int nt = 0; nt < 2; ++nt) {
            const int kout = nt * 16 + lr;
            f32x4 pk;
#pragma unroll
            for (int rr = 0; rr < 4; ++rr) pk[rr] = acc2[nt][rr] + bias2[nt];
            const int mb = wave * 16 + lq * 4;
            const size_t off = ((size_t)(b * KC + kout) * HH + y) * WW + x0 + mb;
            *(f32x4*)&outg[off] = pk;
        }

        // ---------- commit prefetched row y+2 into slot S3 ----------
        if (r < 7) {
            *(short8*)&z_lds[(S3 * 34 + l + 1) * 40 + o * 8] = pack8(mv8);
            if (tid < 8) {
                const int side = tid & 1, oct = tid >> 1;
                short8 hv = *(const short8*)&halo_lds[(r * 2 + side) * 32 + oct * 8];
                *(short8*)&z_lds[(S3 * 34 + side * 33) * 40 + oct * 8] = hv;
            }
        }
        BARRIER();   // commit visible; h-reads done (h rewritten next iter)
    }
}

extern "C" void kernel_launch(void* const* d_in, const int* in_sizes, int n_in,
                              void* d_out, int out_size, void* d_ws, size_t ws_size,
                              hipStream_t stream)
{
    const float* z  = (const float*)d_in[0];
    const float* W1 = (const float*)d_in[1];
    const float* b1 = (const float*)d_in[2];
    const float* W2 = (const float*)d_in[3];
    const float* b2 = (const float*)d_in[4];
    float* out = (float*)d_out;
    unsigned short* w1t = (unsigned short*)d_ws;                // 73728 B
    unsigned short* w2t = (unsigned short*)d_ws + 9 * HID * KC; // + 8192 B

    hipLaunchKernelGGL(prep_weights, dim3(160), dim3(256), 0, stream, W1, W2, w1t, w2t);
    hipLaunchKernelGGL(local_pred_kernel, dim3(8 * 32 * 8), dim3(128), 0, stream,
                       z, w1t, b1, w2t, b2, out);
}

// Round 8
// 212.703 us; speedup vs baseline: 1.7943x; 1.0707x over previous
//
#include <hip/hip_runtime.h>

// LocalPredictor: 3x3 conv (32->128, center masked) + ReLU + 1x1 conv (128->32)
// B=8, k=32, H=W=256, HID=128. fp32 in/out (values bf16-exact) -> bf16 MFMA.
// v13 = v7 (109us) with +25% residency: 5 blocks/CU (20 waves) instead of 4.
//  - 3-slot z ring (commit moved after mid-barrier: all z-reads done) -5.3KB
//  - z c-stride 36 shorts (8B-aligned -> b64 pairs, v7 h-path precedent) -1.6KB
//  - LDS 31.9KB -> 5 x ~32.3KB <= 160KB; grid 1280 = 8b x 40yt x 4xt = 5/CU
//    exactly (y-tiles: 16 of 7 rows + 24 of 6 rows = 256)
//  - memory shape of v7 kept (x-tile 64; v12 proved 32 costs +60MB HBM)
//  - fragment layouts / tap order / k-order byte-identical to v7 numerics

#define KC 32
#define HH 256
#define WW 256
#define HID 128
#define ZSTR 36              // z c-stride (shorts): 72B rows
#define ZSLOT (66 * ZSTR)    // 2376 shorts per row-slot
#define HSTR 132             // h_lds leading dim (shorts), v7-proven

typedef __attribute__((ext_vector_type(8))) short short8;
typedef __attribute__((ext_vector_type(4))) float f32x4;

// LDS-visibility barrier WITHOUT vmcnt drain: global loads/stores stay in flight.
#define BARRIER() asm volatile("s_waitcnt lgkmcnt(0)\n\ts_barrier" ::: "memory")
#define SCHED_FENCE() asm volatile("" ::: "memory")

__device__ __forceinline__ unsigned short f2bf(float f) {
    union { float f; unsigned int i; } x; x.f = f;
    unsigned int r = x.i + 0x7FFFu + ((x.i >> 16) & 1u);  // RNE
    return (unsigned short)(r >> 16);
}

// pack 8 bf16-exact floats -> short8 (truncate = exact)
__device__ __forceinline__ short8 pack8(const float* v) {
    union { short8 s; unsigned int u[4]; } w;
    union { float f; unsigned int i; } uu[8];
#pragma unroll
    for (int j = 0; j < 8; ++j) uu[j].f = v[j];
#pragma unroll
    for (int k = 0; k < 4; ++k)
        w.u[k] = __builtin_amdgcn_perm(uu[2 * k + 1].i, uu[2 * k].i, 0x07060302u);
    return w.s;
}

// ws: w1t bf16[9*HID*KC] | w2t bf16[KC*HID].  w1t[p][d][c], c contiguous.
__global__ void prep_weights(const float* __restrict__ w1,
                             const float* __restrict__ w2,
                             unsigned short* __restrict__ w1t,
                             unsigned short* __restrict__ w2t) {
    int i = blockIdx.x * 256 + threadIdx.x;
    if (i < 9 * HID * KC) {
        int c = i & 31;
        int d = (i >> 5) & 127;
        int p = i >> 12;
        w1t[i] = f2bf(w1[d * (9 * KC) + c * 9 + p]);
    } else if (i < 9 * HID * KC + KC * HID) {
        int j = i - 9 * HID * KC;
        w2t[j] = f2bf(w2[j]);
    }
}

__global__ __launch_bounds__(256, 5) void local_pred_kernel(
    const float* __restrict__ zg,
    const unsigned short* __restrict__ w1t,
    const float* __restrict__ b1g,
    const unsigned short* __restrict__ w2t,
    const float* __restrict__ b2g,
    float* __restrict__ outg)
{
    __shared__ __attribute__((aligned(16))) unsigned short z_lds[3 * ZSLOT];     // 14256 B
    __shared__ __attribute__((aligned(16))) unsigned short h_lds[64 * HSTR];     // 16896 B
    __shared__ __attribute__((aligned(16))) unsigned short halo_lds[6 * 2 * 32]; //   768 B

    const int tid  = threadIdx.x;
    const int bidx = blockIdx.x;
    const int xt   = bidx & 3;
    const int rest = bidx >> 2;        // b*40 + yt
    const int yt   = rest % 40;
    const int b    = rest / 40;
    const int x0   = xt << 6;
    int y0, ys;
    if (yt < 16) { y0 = yt * 7;              ys = 7; }
    else         { y0 = 112 + (yt - 16) * 6; ys = 6; }

    const int l = tid & 63;       // staging x-lane
    const int o = tid >> 6;       // staging c-octet

    const int wave = tid >> 6;
    const int lane = tid & 63;
    const int lr = lane & 15;
    const int lq = lane >> 4;

    const float* zb = zg + (size_t)b * KC * HH * WW;

    // ---------------- prologue: sequential fenced rounds (low reg pressure) ----------------
    // main rows y0-1 .. y0+1 -> slots 0,1,2  (slot(g) = (g - y0 + 1) mod 3)
#pragma unroll
    for (int dy = 0; dy < 3; ++dy) {
        const int gy = y0 - 1 + dy;
        const bool ok = (unsigned)gy < (unsigned)HH;
        const int gyc = ok ? gy : 0;
        const float* p = zb + ((size_t)(o * 8) * HH + gyc) * WW + x0 + l;
        float t8[8];
#pragma unroll
        for (int j = 0; j < 8; ++j) t8[j] = ok ? p[(size_t)j * HH * WW] : 0.f;
        *(short8*)&z_lds[(dy * 66 + l + 1) * ZSTR + o * 8] = pack8(t8);
        SCHED_FENCE();
    }
    // near halo (rows y0-1..y0+1): tid<24 -> (side, c-octet, dy)
    {
        const int s = tid & 1, oc = (tid >> 1) & 3, dy = tid >> 3;
        const int gy = y0 - 1 + dy;
        const int gx = x0 - 1 + s * 65;
        const bool ok = (tid < 24) && ((unsigned)gy < (unsigned)HH) &&
                        ((unsigned)gx < (unsigned)WW);
        const float* q = zb + ((size_t)(oc * 8) * HH + (ok ? gy : 0)) * WW + (ok ? gx : 0);
        float t8[8];
#pragma unroll
        for (int j = 0; j < 8; ++j) t8[j] = ok ? q[(size_t)j * HH * WW] : 0.f;
        if (tid < 24)
            *(short8*)&z_lds[(dy * 66 + s * 65) * ZSTR + oc * 8] = pack8(t8);
        SCHED_FENCE();
    }
    // far halo (rows y0+2..y0+ys): tid in [64,64+8*(ys-1)) -> (side, c-octet, row)
    {
        const int fi = tid - 64;
        const int s = fi & 1, oc = (fi >> 1) & 3, fr = fi >> 3;
        const int gy = y0 + 2 + fr;
        const int gx = x0 - 1 + s * 65;
        const bool act = (tid >= 64) && (fr <= ys - 2);
        const bool ok = act && (gy < HH) && ((unsigned)gx < (unsigned)WW);
        const float* q = zb + ((size_t)(oc * 8) * HH + (ok ? gy : 0)) * WW + (ok ? gx : 0);
        float t8[8];
#pragma unroll
        for (int j = 0; j < 8; ++j) t8[j] = ok ? q[(size_t)j * HH * WW] : 0.f;
        if (act)
            *(short8*)&halo_lds[(fr * 2 + s) * 32 + oc * 8] = pack8(t8);
        SCHED_FENCE();
    }

    // hoisted biases (4 regs)
    float bias1[2], bias2[2];
#pragma unroll
    for (int nt = 0; nt < 2; ++nt) bias1[nt] = b1g[wave * 32 + nt * 16 + lr];
#pragma unroll
    for (int nt = 0; nt < 2; ++nt) bias2[nt] = b2g[nt * 16 + lr];

    BARRIER();

    const int tap_di[8] = {0, 0, 0, 1, 1, 2, 2, 2};
    const int tap_dj[8] = {0, 1, 2, 0, 2, 0, 1, 2};

    float mv8[8];   // single distance-1 prefetch buffer

#define ITER(rr_)                                                                 \
    {                                                                             \
        const int y = y0 + (rr_);                                                 \
        /* issue prefetch: row y+2 (committed after mid-barrier) */               \
        if ((rr_) < ys - 1) {                                                     \
            const int gy = y + 2;                                                 \
            const bool ok = gy < HH;                                              \
            const float* p = zb + ((size_t)(o * 8) * HH + (ok ? gy : 0)) * WW + x0 + l; \
            _Pragma("unroll")                                                     \
            for (int j = 0; j < 8; ++j) mv8[j] = ok ? p[(size_t)j * HH * WW] : 0.f; \
        }                                                                         \
        SCHED_FENCE();                                                            \
        /* GEMM1: per wave M=64 (mt 0..3), N=32 quarter (nt 0..1) */              \
        f32x4 acc[4][2];                                                          \
        _Pragma("unroll")                                                         \
        for (int mt = 0; mt < 4; ++mt)                                            \
            _Pragma("unroll")                                                     \
            for (int nt = 0; nt < 2; ++nt)                                        \
                acc[mt][nt] = (f32x4){0.f, 0.f, 0.f, 0.f};                        \
        const int rowoff[3] = {(((rr_) + 0) % 3) * ZSLOT,                         \
                               (((rr_) + 1) % 3) * ZSLOT,                         \
                               (((rr_) + 2) % 3) * ZSLOT};                        \
        _Pragma("unroll")                                                         \
        for (int t = 0; t < 8; ++t) {                                             \
            const int di = tap_di[t], dj = tap_dj[t];                             \
            const int p = di * 3 + dj;                                            \
            short8 afr[4];                                                        \
            _Pragma("unroll")                                                     \
            for (int mt = 0; mt < 4; ++mt)                                        \
                afr[mt] = *(const short8*)&z_lds[rowoff[di] + (mt * 16 + lr + dj) * ZSTR + lq * 8]; \
            short8 bfr[2];                                                        \
            _Pragma("unroll")                                                     \
            for (int nt = 0; nt < 2; ++nt)                                        \
                bfr[nt] = *(const short8*)&w1t[p * (HID * KC) + (wave * 32 + nt * 16 + lr) * KC + lq * 8]; \
            _Pragma("unroll")                                                     \
            for (int nt = 0; nt < 2; ++nt)                                        \
                _Pragma("unroll")                                                 \
                for (int mt = 0; mt < 4; ++mt)                                    \
                    acc[mt][nt] = __builtin_amdgcn_mfma_f32_16x16x32_bf16(        \
                        afr[mt], bfr[nt], acc[mt][nt], 0, 0, 0);                  \
        }                                                                         \
        /* epilogue1: +b1, ReLU, bf16 -> h */                                     \
        _Pragma("unroll")                                                         \
        for (int nt = 0; nt < 2; ++nt) {                                          \
            const int d = wave * 32 + nt * 16 + lr;                               \
            _Pragma("unroll")                                                     \
            for (int mt = 0; mt < 4; ++mt)                                        \
                _Pragma("unroll")                                                 \
                for (int rr = 0; rr < 4; ++rr) {                                  \
                    float v = acc[mt][nt][rr] + bias1[nt];                        \
                    v = v > 0.f ? v : 0.f;                                        \
                    const int m = mt * 16 + lq * 4 + rr;                          \
                    h_lds[m * HSTR + d] = f2bf(v);                                \
                }                                                                 \
        }                                                                         \
        BARRIER();   /* h ready; ALL waves' GEMM1 z-reads complete */             \
        /* commit prefetched row y+2 into slot rr_%3 (just-vacated row y-1) */    \
        if ((rr_) < ys - 1) {                                                     \
            *(short8*)&z_lds[(((rr_) % 3) * 66 + l + 1) * ZSTR + o * 8] = pack8(mv8); \
            if (tid < 8) {                                                        \
                const int side = tid & 1, oct = tid >> 1;                         \
                short8 hv = *(const short8*)&halo_lds[((rr_) * 2 + side) * 32 + oct * 8]; \
                *(short8*)&z_lds[(((rr_) % 3) * 66 + side * 65) * ZSTR + oct * 8] = hv; \
            }                                                                     \
        }                                                                         \
        /* GEMM2: M=64, N=32, K=128 (B from L1-hot w2t) */                        \
        f32x4 acc2[2];                                                            \
        acc2[0] = (f32x4){0.f, 0.f, 0.f, 0.f};                                    \
        acc2[1] = (f32x4){0.f, 0.f, 0.f, 0.f};                                    \
        const int m2 = wave * 16 + lr;                                            \
        _Pragma("unroll")                                                         \
        for (int k4 = 0; k4 < 4; ++k4) {                                          \
            short8 afr2 = *(const short8*)&h_lds[m2 * HSTR + k4 * 32 + lq * 8];   \
            _Pragma("unroll")                                                     \
            for (int nt = 0; nt < 2; ++nt) {                                      \
                short8 bfr2 = *(const short8*)&w2t[(nt * 16 + lr) * HID + k4 * 32 + lq * 8]; \
                acc2[nt] = __builtin_amdgcn_mfma_f32_16x16x32_bf16(afr2, bfr2, acc2[nt], 0, 0, 0); \
            }                                                                     \
        }                                                                         \
        /* epilogue2: +b2, 16B coalesced stores */                                \
        _Pragma("unroll")                                                         \
        for (int nt = 0; nt < 2; ++nt) {                                          \
            const int kout = nt * 16 + lr;                                        \
            f32x4 pk;                                                             \
            _Pragma("unroll")                                                     \
            for (int rr = 0; rr < 4; ++rr) pk[rr] = acc2[nt][rr] + bias2[nt];     \
            const int mb = wave * 16 + lq * 4;                                    \
            const size_t off = ((size_t)(b * KC + kout) * HH + y) * WW + x0 + mb; \
            *(f32x4*)&outg[off] = pk;                                             \
        }                                                                         \
        BARRIER();   /* commit visible; h-reads done (h rewritten next iter) */   \
    }

#pragma unroll
    for (int r = 0; r < 6; ++r) ITER(r);
    if (ys == 7) ITER(6);
#undef ITER
}

extern "C" void kernel_launch(void* const* d_in, const int* in_sizes, int n_in,
                              void* d_out, int out_size, void* d_ws, size_t ws_size,
                              hipStream_t stream)
{
    const float* z  = (const float*)d_in[0];
    const float* W1 = (const float*)d_in[1];
    const float* b1 = (const float*)d_in[2];
    const float* W2 = (const float*)d_in[3];
    const float* b2 = (const float*)d_in[4];
    float* out = (float*)d_out;
    unsigned short* w1t = (unsigned short*)d_ws;                // 73728 B
    unsigned short* w2t = (unsigned short*)d_ws + 9 * HID * KC; // + 8192 B

    hipLaunchKernelGGL(prep_weights, dim3(160), dim3(256), 0, stream, W1, W2, w1t, w2t);
    hipLaunchKernelGGL(local_pred_kernel, dim3(8 * 40 * 4), dim3(256), 0, stream,
                       z, w1t, b1, w2t, b2, out);
}